// Round 1
// 964.793 us; speedup vs baseline: 1.2124x; 1.2124x over previous
//
#include <hip/hip_runtime.h>
#include <stdint.h>

#define HID 4096
#define NHD 32
#define HD  128
#define BB  2
#define SS  2048
#define BSZ (BB*SS)      // 4096 rows (b,s)
#define N3  (3*HID)      // 12288

typedef __bf16 bf16x8 __attribute__((ext_vector_type(8)));
typedef __bf16 bf16x4 __attribute__((ext_vector_type(4)));
typedef float  f32x4  __attribute__((ext_vector_type(4)));

#define MFMA16(A,B,C) __builtin_amdgcn_mfma_f32_16x16x32_bf16((A),(B),(C),0,0,0)

// async global->LDS, 16B per lane; LDS dest must be wave-uniform base + lane*16
__device__ __forceinline__ void gl_lds16(const __bf16* g, __bf16* l) {
  __builtin_amdgcn_global_load_lds(
      (__attribute__((address_space(1))) void*)g,
      (__attribute__((address_space(3))) void*)l, 16, 0, 0);
}

__device__ __forceinline__ void block_bar() {
  __builtin_amdgcn_sched_barrier(0);
  __builtin_amdgcn_s_barrier();
  __builtin_amdgcn_sched_barrier(0);
}
#define LGKM0() do { asm volatile("s_waitcnt lgkmcnt(0)" ::: "memory"); \
                     __builtin_amdgcn_sched_barrier(0); } while (0)
#define VMC(n)  do { asm volatile("s_waitcnt vmcnt(" #n ")" ::: "memory"); \
                     __builtin_amdgcn_sched_barrier(0); } while (0)

// ---------------- elementwise fp32 -> bf16 ----------------
__global__ void cvt_bf16(const float* __restrict__ in, __bf16* __restrict__ out, int n) {
  int i = (blockIdx.x * blockDim.x + threadIdx.x) * 4;
  if (i >= n) return;
  float4 v = *(const float4*)(in + i);
  bf16x4 r;
  r[0] = (__bf16)v.x; r[1] = (__bf16)v.y; r[2] = (__bf16)v.z; r[3] = (__bf16)v.w;
  *(bf16x4*)(out + i) = r;
}

// ------- fp32 (R,C) -> bf16 (C,R) transpose-convert, 64x64 tile, vectorized
__global__ void transp_cvt(const float* __restrict__ in, __bf16* __restrict__ out,
                           int R, int C) {
  __shared__ float t[64 * 65];
  int c0 = blockIdx.x * 64, r0 = blockIdx.y * 64;
  int tx = threadIdx.x & 15, ty = threadIdx.x >> 4;   // 16 x 16
  for (int j = 0; j < 4; ++j) {
    float4 v = *(const float4*)(in + (size_t)(r0 + ty + 16 * j) * C + c0 + tx * 4);
    float* d = t + (ty + 16 * j) * 65 + tx * 4;
    d[0] = v.x; d[1] = v.y; d[2] = v.z; d[3] = v.w;
  }
  __syncthreads();
  for (int j = 0; j < 4; ++j) {
    int cc = ty + 16 * j;                 // transposed output row
    bf16x4 o4;
    for (int e = 0; e < 4; ++e) o4[e] = (__bf16)t[(tx * 4 + e) * 65 + cc];
    *(bf16x4*)(out + (size_t)(c0 + cc) * R + r0 + tx * 4) = o4;
  }
}

// =================== 256x256 8-phase GEMM core (BK=64, 8 waves) ============
// Per-wave output 128x64 (8 m-frags x 4 n-frags of 16x16).
// LDS: 2 buffers x {A half0/half1, B half0/half1} of 128x64 bf16 = 128 KiB.
// Staging: linear LDS dest, XOR-swizzled global source (chunk ^= row&7).
// Phases (per iter, 2 K-tiles): Gray quadrant order Q(m0,n0),Q(m0,n1),
// Q(m1,n1),Q(m1,n0) per tile; each phase also stages 1 half-tile; vmcnt(6)
// only at phases 4 and 8 (3 half-tiles stay in flight across barriers).

__device__ __forceinline__ void ld_a4(bf16x8 a[4][2], const __bf16* base, int row, int quad) {
#pragma unroll
  for (int m = 0; m < 4; ++m) {
    const int rr = row + m * 16;
    const int sw = rr & 7;
#pragma unroll
    for (int kk = 0; kk < 2; ++kk)
      a[m][kk] = *(const bf16x8*)(base + rr * 64 + ((kk * 4 + quad) ^ sw) * 8);
  }
}
__device__ __forceinline__ void ld_b2(bf16x8 b[2][2], const __bf16* base, int row, int quad) {
#pragma unroll
  for (int n = 0; n < 2; ++n) {
    const int rr = row + n * 16;
    const int sw = rr & 7;
#pragma unroll
    for (int kk = 0; kk < 2; ++kk)
      b[n][kk] = *(const bf16x8*)(base + rr * 64 + ((kk * 4 + quad) ^ sw) * 8);
  }
}
__device__ __forceinline__ void mma_quad(f32x4 acc[8][4], bf16x8 a[4][2],
                                         bf16x8 b[2][2], int mh, int nh) {
  __builtin_amdgcn_s_setprio(1);
#pragma unroll
  for (int m = 0; m < 4; ++m)
#pragma unroll
    for (int n = 0; n < 2; ++n) {
      f32x4 c = acc[mh * 4 + m][nh * 2 + n];
      c = MFMA16(a[m][0], b[n][0], c);
      c = MFMA16(a[m][1], b[n][1], c);
      acc[mh * 4 + m][nh * 2 + n] = c;
    }
  __builtin_amdgcn_s_setprio(0);
}

__device__ __forceinline__ void core256(const __bf16* __restrict__ Ab,
                                        const __bf16* __restrict__ Bb,
                                        int K, __bf16* smem, f32x4 acc[8][4]) {
  const int tid  = threadIdx.x;
  const int wave = tid >> 6, lane = tid & 63;
  const int quad = lane >> 4, l15 = lane & 15;
  const int arow = ((wave >> 2) * 64) + l15;  // row base within A half-region
  const int brow = ((wave & 3) * 32) + l15;   // row base within B half-region
  const int NKT = K >> 6, NIT = NKT >> 1;

  __bf16* aBuf[2] = { smem,          smem + 16384 };
  __bf16* bBuf[2] = { smem + 32768,  smem + 49152 };

  // per-thread staging offsets (2 x 16B per half-tile)
  const int off0 = tid * 16, off1 = off0 + 8192;
  const int r0 = off0 >> 7, r1 = off1 >> 7;
  const int sO0 = r0 * K + ((((off0 >> 4) & 7) ^ (r0 & 7)) * 8);
  const int sO1 = r1 * K + ((((off1 >> 4) & 7) ^ (r1 & 7)) * 8);
  const int d0 = off0 >> 1, d1 = off1 >> 1;

#define STG_A(buf, half, kt) do { \
    const __bf16* s_ = Ab + (size_t)(half) * 128 * K + (size_t)(kt) * 64; \
    gl_lds16(s_ + sO0, aBuf[buf] + (half) * 8192 + d0); \
    gl_lds16(s_ + sO1, aBuf[buf] + (half) * 8192 + d1); } while (0)
#define STG_B(buf, half, kt) do { \
    const __bf16* s_ = Bb + (size_t)(half) * 128 * K + (size_t)(kt) * 64; \
    gl_lds16(s_ + sO0, bBuf[buf] + (half) * 8192 + d0); \
    gl_lds16(s_ + sO1, bBuf[buf] + (half) * 8192 + d1); } while (0)

  bf16x8 a_r[4][2], bn0[2][2], bn1[2][2];

  // prologue: tile0 [A0,B0,B1,A1]->buf0; tile1 [A0,B0,B1]->buf1
  STG_A(0, 0, 0); STG_B(0, 0, 0); STG_B(0, 1, 0); STG_A(0, 1, 0);
  STG_A(1, 0, 1); STG_B(1, 0, 1); STG_B(1, 1, 1);
  VMC(6);            // tile0 fully landed (tile1's 3 half-tiles may fly)
  block_bar();

  for (int i = 0; i < NIT; ++i) {
    const bool last = (i == NIT - 1);
    const int t1 = 2 * i + 1, t2 = 2 * i + 2, t3 = 2 * i + 3;

    // ---- P1: tile 2i, Q(m0,n0) ----
    ld_a4(a_r, aBuf[0],        arow, quad);
    ld_b2(bn0, bBuf[0],        brow, quad);
    STG_A(1, 1, t1);                       // buf1.A1 <- tile 2i+1 (read at P7)
    block_bar(); LGKM0();
    mma_quad(acc, a_r, bn0, 0, 0);
    block_bar();

    // ---- P2: Q(m0,n1) ----
    ld_b2(bn1, bBuf[0] + 8192, brow, quad);
    if (!last) STG_A(0, 0, t2);            // buf0.A0 <- tile 2i+2
    block_bar(); LGKM0();
    mma_quad(acc, a_r, bn1, 0, 1);
    block_bar();

    // ---- P3: Q(m1,n1) ----
    ld_a4(a_r, aBuf[0] + 8192, arow, quad);
    if (!last) STG_B(0, 0, t2);            // buf0.B0
    block_bar(); LGKM0();
    mma_quad(acc, a_r, bn1, 1, 1);
    block_bar();

    // ---- P4: Q(m1,n0) ----
    if (!last) STG_B(0, 1, t2);            // buf0.B1
    block_bar();
    mma_quad(acc, a_r, bn0, 1, 0);
    if (last) { VMC(0); } else { VMC(6); } // buf1 (tile 2i+1) fully landed
    block_bar();

    // ---- P5: tile 2i+1, Q(m0,n0) ----
    ld_a4(a_r, aBuf[1],        arow, quad);
    ld_b2(bn0, bBuf[1],        brow, quad);
    if (!last) STG_A(0, 1, t2);            // buf0.A1
    block_bar(); LGKM0();
    mma_quad(acc, a_r, bn0, 0, 0);
    block_bar();

    // ---- P6: Q(m0,n1) ----
    ld_b2(bn1, bBuf[1] + 8192, brow, quad);
    if (!last) STG_A(1, 0, t3);            // buf1.A0 <- tile 2i+3
    block_bar(); LGKM0();
    mma_quad(acc, a_r, bn1, 0, 1);
    block_bar();

    // ---- P7: Q(m1,n1) ----
    ld_a4(a_r, aBuf[1] + 8192, arow, quad);
    if (!last) STG_B(1, 0, t3);            // buf1.B0
    block_bar(); LGKM0();
    mma_quad(acc, a_r, bn1, 1, 1);
    block_bar();

    // ---- P8: Q(m1,n0) ----
    if (!last) STG_B(1, 1, t3);            // buf1.B1
    block_bar();
    mma_quad(acc, a_r, bn0, 1, 0);
    VMC(6);                                // buf0 (tile 2i+2) fully landed
    block_bar();
  }
#undef STG_A
#undef STG_B
  // exits with all waves past the final barrier and zero loads outstanding
  // (last iter: VMC(0) at P4, no stages after) -> smem reusable immediately.
}

// epilogue LDS swizzle: 256x256 bf16 tile, chunk ^= (r&31) ^ (r>>5)
// (extra r>>5 bit keeps the V-transpose's stride-8-row column reads
//  from aliasing mod-32 banks)
__device__ __forceinline__ int eswz(int r, int c) {
  return r * 256 + ((((c >> 3) ^ (r & 31) ^ (r >> 5)) & 31) * 8) + (c & 7);
}

// ---------------- fused QKV GEMM + bias + RoPE + q/k/v scatter -------------
__global__ __launch_bounds__(512, 2) void gemm_qkv(
    const __bf16* __restrict__ A, const __bf16* __restrict__ Bt,
    const float* __restrict__ bias, const int* __restrict__ pos,
    __bf16* __restrict__ qr, __bf16* __restrict__ kr, __bf16* __restrict__ vt,
    int M, int N, int K) {
  __shared__ __bf16 smem[65536];          // 128 KiB
  const int tid = threadIdx.x;
  const int wave = tid >> 6, lane = tid & 63;
  const int quad = lane >> 4, l15 = lane & 15;
  const int wm = (wave >> 2) * 64, wn = (wave & 3) * 32;

  // bijective XCD swizzle: 768 blocks, 96/XCD, m-fast within chunk
  const int orig = blockIdx.x;
  const int swz = (orig & 7) * 96 + (orig >> 3);
  const int m0 = (swz & 15) * 256;
  const int n0 = (swz >> 4) * 256;

  f32x4 acc[8][4];
#pragma unroll
  for (int i = 0; i < 8; ++i)
#pragma unroll
    for (int j = 0; j < 4; ++j) acc[i][j] = (f32x4){0.f, 0.f, 0.f, 0.f};

  core256(A + (size_t)m0 * K, Bt + (size_t)n0 * K, K, smem, acc);

  // ---- acc + bias -> LDS (swizzled) ----
#pragma unroll
  for (int ni = 0; ni < 4; ++ni) {
    const int scol = (ni >> 1) * 128 + wn + (ni & 1) * 16 + l15;
    const float bv = bias[n0 + scol];
#pragma unroll
    for (int mi = 0; mi < 8; ++mi) {
      const int rbase = (mi >> 2) * 128 + wm + (mi & 3) * 16 + quad * 4;
#pragma unroll
      for (int rr = 0; rr < 4; ++rr)
        smem[eswz(rbase + rr, scol)] = (__bf16)(acc[mi][ni][rr] + bv);
    }
  }
  __syncthreads();

  const int reg = n0 >> 12;               // 0=q 1=k 2=v
  const int h0  = (n0 & 4095) >> 7;       // tile covers heads h0, h0+1
  const int b   = m0 >> 11;
  const int s0  = m0 & 2047;

  if (reg == 2) {
    // V: store transposed (d, s), 16B/lane coalesced over s
    __bf16* dst = vt + (size_t)(b * NHD + h0) * HD * SS;
    const int sg = tid & 31, cb = tid >> 5;     // 32 s-groups x 16 col-bases
    for (int p = 0; p < 16; ++p) {
      const int c = cb + 16 * p;                // 0..255
      bf16x8 v8;
#pragma unroll
      for (int e = 0; e < 8; ++e) v8[e] = smem[eswz(sg * 8 + e, c)];
      *(bf16x8*)(dst + (size_t)(c >> 7) * HD * SS + (size_t)(c & 127) * SS +
                 s0 + sg * 8) = v8;
    }
  } else {
    // Q/K: RoPE in fp32, write (b,h,s,d); Q pre-scaled by 1/sqrt(d)
    __bf16* dst = (reg == 0 ? qr : kr) + (size_t)(b * NHD + h0) * SS * HD;
    const float osc = (reg == 0) ? 0.08838834764831845f : 1.0f;
    const int d2 = tid & 63, rb = (tid >> 6) * 32;
    const float freq = expf(-0.14391156831212787f * (float)d2);  // 1e4^(-d2/64)
    for (int i = 0; i < 32; ++i) {
      const int r = rb + i;
      const float p = (float)pos[b * SS + s0 + r];
      float sn, cs;
      sincosf(p * freq, &sn, &cs);
#pragma unroll
      for (int hs = 0; hs < 2; ++hs) {
        const float x1 = (float)smem[eswz(r, hs * 128 + d2)];
        const float x2 = (float)smem[eswz(r, hs * 128 + d2 + 64)];
        __bf16* dr = dst + (size_t)hs * SS * HD + (size_t)(s0 + r) * HD;
        dr[d2]      = (__bf16)((x1 * cs - x2 * sn) * osc);
        dr[d2 + 64] = (__bf16)((x2 * cs + x1 * sn) * osc);
      }
    }
  }
}

// ---------------- plain bf16 GEMM (output projection): C = A * Bt^T --------
__global__ __launch_bounds__(512, 2) void gemm_bt(
    const __bf16* __restrict__ A, const __bf16* __restrict__ Bt,
    float* __restrict__ Cout, int M, int N, int K) {
  __shared__ __bf16 smem[65536];
  const int tid = threadIdx.x;
  const int wave = tid >> 6, lane = tid & 63;
  const int quad = lane >> 4, l15 = lane & 15;
  const int wm = (wave >> 2) * 64, wn = (wave & 3) * 32;

  const int orig = blockIdx.x;                  // 256 blocks, 32/XCD
  const int swz = (orig & 7) * 32 + (orig >> 3);
  const int m0 = (swz & 15) * 256;
  const int n0 = (swz >> 4) * 256;

  f32x4 acc[8][4];
#pragma unroll
  for (int i = 0; i < 8; ++i)
#pragma unroll
    for (int j = 0; j < 4; ++j) acc[i][j] = (f32x4){0.f, 0.f, 0.f, 0.f};

  core256(A + (size_t)m0 * K, Bt + (size_t)n0 * K, K, smem, acc);

#pragma unroll
  for (int mi = 0; mi < 8; ++mi) {
    const int row = m0 + (mi >> 2) * 128 + wm + (mi & 3) * 16 + quad * 4;
#pragma unroll
    for (int ni = 0; ni < 4; ++ni) {
      const int col = n0 + (ni >> 1) * 128 + wn + (ni & 1) * 16 + l15;
#pragma unroll
      for (int rr = 0; rr < 4; ++rr)
        Cout[(size_t)(row + rr) * N + col] = acc[mi][ni][rr];
    }
  }
}

// ---------------- flash attention, causal, per (b,h, 128-row q tile) -------
// (unchanged this round)
__global__ __launch_bounds__(256, 2) void flash_attn(
    const __bf16* __restrict__ qr, const __bf16* __restrict__ kr,
    const __bf16* __restrict__ vt, __bf16* __restrict__ ctx) {
  __shared__ __bf16 sKP[4 * 32 * 136];  // 34816 B; first 16384 el = K tile
  __shared__ __bf16 sV[128 * 128];
  const int bh = blockIdx.x;            // 0..63
  const int qt = 15 - blockIdx.y;       // long blocks dispatch first
  const int b = bh >> 5, h = bh & 31;
  const int tid = threadIdx.x;
  const int wave = tid >> 6, lane = tid & 63;
  const int quad = lane >> 4, l15 = lane & 15;
  const int q0 = qt * 128;

  const __bf16* qbase = qr + (size_t)bh * SS * HD;
  const __bf16* kbase = kr + (size_t)bh * SS * HD;
  const __bf16* vbase = vt + (size_t)bh * HD * SS;
  __bf16* sK = sKP;
  __bf16* pw = sKP + wave * (32 * 136);

  bf16x8 qf[2][4];
  for (int im = 0; im < 2; ++im) {
    int row = q0 + wave * 32 + im * 16 + l15;
    for (int ks = 0; ks < 4; ++ks)
      qf[im][ks] = *(const bf16x8*)(qbase + (size_t)row * HD + ks * 32 + quad * 8);
  }

  f32x4 o[2][8];
  for (int im = 0; im < 2; ++im)
    for (int jd = 0; jd < 8; ++jd)
      o[im][jd] = (f32x4){0.f, 0.f, 0.f, 0.f};
  float l_i[2][4];
  for (int im = 0; im < 2; ++im)
    for (int rg = 0; rg < 4; ++rg) l_i[im][rg] = 0.f;

  for (int kt = 0; kt <= qt; ++kt) {
    const int k0 = kt * 128;
    __syncthreads();   // #1: prior iter done reading sV / P region
    for (int i = 0; i < 8; ++i) {
      int off = tid * 16 + i * 4096;    // byte offset in 32KB tile
      int r  = off >> 8;                // 256B per row (128 bf16)
      int cl = (off >> 4) & 15;         // 16B chunk slot within row
      int cg = (cl & 8) | ((cl & 7) ^ (r & 7));   // swizzled source chunk
      gl_lds16(kbase + (size_t)(k0 + r) * HD + cg * 8, sK + (off >> 1));
      gl_lds16(vbase + (size_t)r * SS + k0 + cg * 8,   sV + (off >> 1));
    }
    __syncthreads();   // #2: staging drained

    // S = Q K^T  (Q pre-scaled by 1/sqrt(d))
    f32x4 s[2][8];
    for (int im = 0; im < 2; ++im)
      for (int jn = 0; jn < 8; ++jn)
        s[im][jn] = (f32x4){0.f, 0.f, 0.f, 0.f};
    for (int ks = 0; ks < 4; ++ks) {
      bf16x8 kf[8];
      for (int jn = 0; jn < 8; ++jn) {
        int row = jn * 16 + l15;
        int c = ks * 4 + quad;
        int p = (c & 8) | ((c & 7) ^ (row & 7));
        kf[jn] = *(const bf16x8*)(sK + row * 128 + p * 8);
      }
      for (int im = 0; im < 2; ++im)
        for (int jn = 0; jn < 8; ++jn)
          s[im][jn] = MFMA16(qf[im][ks], kf[jn], s[im][jn]);
    }
    __syncthreads();   // #3: all sK reads done; P region may be written

    // softmax without running max (C layout: row = quad*4+rg, col = lane&15)
    const bool diag = (kt == qt);
    for (int im = 0; im < 2; ++im)
      for (int rg = 0; rg < 4; ++rg) {
        int rowg = q0 + wave * 32 + im * 16 + quad * 4 + rg;
        float rs = 0.f;
        for (int jn = 0; jn < 8; ++jn) {
          float p = (diag && (k0 + jn * 16 + l15) > rowg)
                        ? 0.f : __expf(s[im][jn][rg]);
          s[im][jn][rg] = p;
          rs += p;
        }
        for (int d = 1; d < 16; d <<= 1) rs += __shfl_xor(rs, d);
        l_i[im][rg] += rs;
      }

    // P -> LDS (C layout to A layout round-trip; own-wave region)
    for (int im = 0; im < 2; ++im)
      for (int jn = 0; jn < 8; ++jn)
        for (int rg = 0; rg < 4; ++rg)
          pw[(im * 16 + quad * 4 + rg) * 136 + jn * 16 + l15] =
              (__bf16)s[im][jn][rg];

    // O += P V
    for (int ks = 0; ks < 4; ++ks) {
      bf16x8 pf[2], vf[8];
      for (int im = 0; im < 2; ++im)
        pf[im] = *(const bf16x8*)(pw + (im * 16 + l15) * 136 + ks * 32 + quad * 8);
      for (int jd = 0; jd < 8; ++jd) {
        int row = jd * 16 + l15;
        int c = ks * 4 + quad;
        int p = (c & 8) | ((c & 7) ^ (row & 7));
        vf[jd] = *(const bf16x8*)(sV + row * 128 + p * 8);
      }
      for (int im = 0; im < 2; ++im)
        for (int jd = 0; jd < 8; ++jd)
          o[im][jd] = MFMA16(pf[im], vf[jd], o[im][jd]);
    }
  }

  // epilogue: O/l -> ctx (B,S,H) bf16
  __bf16* cb = ctx + (size_t)(b * SS) * HID + h * HD;
  for (int im = 0; im < 2; ++im)
    for (int rg = 0; rg < 4; ++rg) {
      float inv = 1.0f / l_i[im][rg];
      int row = q0 + wave * 32 + im * 16 + quad * 4 + rg;
      for (int jd = 0; jd < 8; ++jd)
        cb[(size_t)row * HID + jd * 16 + l15] = (__bf16)(o[im][jd][rg] * inv);
    }
}

// ---------------- launcher ----------------
extern "C" void kernel_launch(void* const* d_in, const int* in_sizes, int n_in,
                              void* d_out, int out_size, void* d_ws, size_t ws_size,
                              hipStream_t stream) {
  const float* hs   = (const float*)d_in[0];
  const int*   pos  = (const int*)d_in[1];
  const float* Wqkv = (const float*)d_in[2];
  const float* bqkv = (const float*)d_in[3];
  const float* Wo   = (const float*)d_in[4];

  // workspace layout (256 MiB total):
  //  [0,32M)     hsb (bf16 hidden) -> reused as ctx after gemm_qkv/flash
  //  [32M,128M)  wqkvT (12288x4096 bf16) — live through gemm_qkv
  //  [128M,160M) woT (4096x4096 bf16)
  //  [160M,192M) qr   [192M,224M) kr   [224M,256M) vt
  char* ws = (char*)d_ws;
  const size_t M32 = 33554432;
  __bf16* hsb   = (__bf16*)(ws);
  __bf16* wqkvT = (__bf16*)(ws + M32);
  __bf16* woT   = (__bf16*)(ws + 4 * M32);
  __bf16* qr    = (__bf16*)(ws + 5 * M32);
  __bf16* kr    = (__bf16*)(ws + 6 * M32);
  __bf16* vt    = (__bf16*)(ws + 7 * M32);
  __bf16* ctx   = hsb;

  cvt_bf16<<<(BSZ * HID) / 1024, 256, 0, stream>>>(hs, hsb, BSZ * HID);
  transp_cvt<<<dim3(N3 / 64, HID / 64), 256, 0, stream>>>(Wqkv, wqkvT, HID, N3);
  transp_cvt<<<dim3(HID / 64, HID / 64), 256, 0, stream>>>(Wo, woT, HID, HID);
  gemm_qkv<<<768, 512, 0, stream>>>(hsb, wqkvT, bqkv, pos, qr, kr, vt,
                                    BSZ, N3, HID);
  flash_attn<<<dim3(BB * NHD, SS / 128), 256, 0, stream>>>(qr, kr, vt, ctx);
  gemm_bt<<<256, 512, 0, stream>>>(ctx, woT, (float*)d_out, BSZ, HID, HID);
}

// Round 2
// 955.406 us; speedup vs baseline: 1.2243x; 1.0098x over previous
//
#include <hip/hip_runtime.h>
#include <stdint.h>

#define HID 4096
#define NHD 32
#define HD  128
#define BB  2
#define SS  2048
#define BSZ (BB*SS)      // 4096 rows (b,s)
#define N3  (3*HID)      // 12288

typedef __bf16 bf16x8 __attribute__((ext_vector_type(8)));
typedef __bf16 bf16x4 __attribute__((ext_vector_type(4)));
typedef float  f32x4  __attribute__((ext_vector_type(4)));

#define MFMA16(A,B,C) __builtin_amdgcn_mfma_f32_16x16x32_bf16((A),(B),(C),0,0,0)

// async global->LDS, 16B per lane; LDS dest must be wave-uniform base + lane*16
__device__ __forceinline__ void gl_lds16(const __bf16* g, __bf16* l) {
  __builtin_amdgcn_global_load_lds(
      (__attribute__((address_space(1))) void*)g,
      (__attribute__((address_space(3))) void*)l, 16, 0, 0);
}

__device__ __forceinline__ void block_bar() {
  __builtin_amdgcn_sched_barrier(0);
  __builtin_amdgcn_s_barrier();
  __builtin_amdgcn_sched_barrier(0);
}
#define LGKM0() do { asm volatile("s_waitcnt lgkmcnt(0)" ::: "memory"); \
                     __builtin_amdgcn_sched_barrier(0); } while (0)
#define VMC(n)  do { asm volatile("s_waitcnt vmcnt(" #n ")" ::: "memory"); \
                     __builtin_amdgcn_sched_barrier(0); } while (0)

// ---------------- elementwise fp32 -> bf16 ----------------
__global__ void cvt_bf16(const float* __restrict__ in, __bf16* __restrict__ out, int n) {
  int i = (blockIdx.x * blockDim.x + threadIdx.x) * 4;
  if (i >= n) return;
  float4 v = *(const float4*)(in + i);
  bf16x4 r;
  r[0] = (__bf16)v.x; r[1] = (__bf16)v.y; r[2] = (__bf16)v.z; r[3] = (__bf16)v.w;
  *(bf16x4*)(out + i) = r;
}

// ------- fp32 (R,C) -> bf16 (C,R) transpose-convert, 64x64 tile, vectorized
__global__ void transp_cvt(const float* __restrict__ in, __bf16* __restrict__ out,
                           int R, int C) {
  __shared__ float t[64 * 65];
  int c0 = blockIdx.x * 64, r0 = blockIdx.y * 64;
  int tx = threadIdx.x & 15, ty = threadIdx.x >> 4;   // 16 x 16
  for (int j = 0; j < 4; ++j) {
    float4 v = *(const float4*)(in + (size_t)(r0 + ty + 16 * j) * C + c0 + tx * 4);
    float* d = t + (ty + 16 * j) * 65 + tx * 4;
    d[0] = v.x; d[1] = v.y; d[2] = v.z; d[3] = v.w;
  }
  __syncthreads();
  for (int j = 0; j < 4; ++j) {
    int cc = ty + 16 * j;                 // transposed output row
    bf16x4 o4;
    for (int e = 0; e < 4; ++e) o4[e] = (__bf16)t[(tx * 4 + e) * 65 + cc];
    *(bf16x4*)(out + (size_t)(c0 + cc) * R + r0 + tx * 4) = o4;
  }
}

// =================== 256x256 8-phase GEMM core (BK=64, 8 waves) ============
// (unchanged from round 1)

__device__ __forceinline__ void ld_a4(bf16x8 a[4][2], const __bf16* base, int row, int quad) {
#pragma unroll
  for (int m = 0; m < 4; ++m) {
    const int rr = row + m * 16;
    const int sw = rr & 7;
#pragma unroll
    for (int kk = 0; kk < 2; ++kk)
      a[m][kk] = *(const bf16x8*)(base + rr * 64 + ((kk * 4 + quad) ^ sw) * 8);
  }
}
__device__ __forceinline__ void ld_b2(bf16x8 b[2][2], const __bf16* base, int row, int quad) {
#pragma unroll
  for (int n = 0; n < 2; ++n) {
    const int rr = row + n * 16;
    const int sw = rr & 7;
#pragma unroll
    for (int kk = 0; kk < 2; ++kk)
      b[n][kk] = *(const bf16x8*)(base + rr * 64 + ((kk * 4 + quad) ^ sw) * 8);
  }
}
__device__ __forceinline__ void mma_quad(f32x4 acc[8][4], bf16x8 a[4][2],
                                         bf16x8 b[2][2], int mh, int nh) {
  __builtin_amdgcn_s_setprio(1);
#pragma unroll
  for (int m = 0; m < 4; ++m)
#pragma unroll
    for (int n = 0; n < 2; ++n) {
      f32x4 c = acc[mh * 4 + m][nh * 2 + n];
      c = MFMA16(a[m][0], b[n][0], c);
      c = MFMA16(a[m][1], b[n][1], c);
      acc[mh * 4 + m][nh * 2 + n] = c;
    }
  __builtin_amdgcn_s_setprio(0);
}

__device__ __forceinline__ void core256(const __bf16* __restrict__ Ab,
                                        const __bf16* __restrict__ Bb,
                                        int K, __bf16* smem, f32x4 acc[8][4]) {
  const int tid  = threadIdx.x;
  const int wave = tid >> 6, lane = tid & 63;
  const int quad = lane >> 4, l15 = lane & 15;
  const int arow = ((wave >> 2) * 64) + l15;  // row base within A half-region
  const int brow = ((wave & 3) * 32) + l15;   // row base within B half-region
  const int NKT = K >> 6, NIT = NKT >> 1;

  __bf16* aBuf[2] = { smem,          smem + 16384 };
  __bf16* bBuf[2] = { smem + 32768,  smem + 49152 };

  // per-thread staging offsets (2 x 16B per half-tile)
  const int off0 = tid * 16, off1 = off0 + 8192;
  const int r0 = off0 >> 7, r1 = off1 >> 7;
  const int sO0 = r0 * K + ((((off0 >> 4) & 7) ^ (r0 & 7)) * 8);
  const int sO1 = r1 * K + ((((off1 >> 4) & 7) ^ (r1 & 7)) * 8);
  const int d0 = off0 >> 1, d1 = off1 >> 1;

#define STG_A(buf, half, kt) do { \
    const __bf16* s_ = Ab + (size_t)(half) * 128 * K + (size_t)(kt) * 64; \
    gl_lds16(s_ + sO0, aBuf[buf] + (half) * 8192 + d0); \
    gl_lds16(s_ + sO1, aBuf[buf] + (half) * 8192 + d1); } while (0)
#define STG_B(buf, half, kt) do { \
    const __bf16* s_ = Bb + (size_t)(half) * 128 * K + (size_t)(kt) * 64; \
    gl_lds16(s_ + sO0, bBuf[buf] + (half) * 8192 + d0); \
    gl_lds16(s_ + sO1, bBuf[buf] + (half) * 8192 + d1); } while (0)

  bf16x8 a_r[4][2], bn0[2][2], bn1[2][2];

  // prologue: tile0 [A0,B0,B1,A1]->buf0; tile1 [A0,B0,B1]->buf1
  STG_A(0, 0, 0); STG_B(0, 0, 0); STG_B(0, 1, 0); STG_A(0, 1, 0);
  STG_A(1, 0, 1); STG_B(1, 0, 1); STG_B(1, 1, 1);
  VMC(6);            // tile0 fully landed (tile1's 3 half-tiles may fly)
  block_bar();

  for (int i = 0; i < NIT; ++i) {
    const bool last = (i == NIT - 1);
    const int t1 = 2 * i + 1, t2 = 2 * i + 2, t3 = 2 * i + 3;

    // ---- P1: tile 2i, Q(m0,n0) ----
    ld_a4(a_r, aBuf[0],        arow, quad);
    ld_b2(bn0, bBuf[0],        brow, quad);
    STG_A(1, 1, t1);                       // buf1.A1 <- tile 2i+1 (read at P7)
    block_bar(); LGKM0();
    mma_quad(acc, a_r, bn0, 0, 0);
    block_bar();

    // ---- P2: Q(m0,n1) ----
    ld_b2(bn1, bBuf[0] + 8192, brow, quad);
    if (!last) STG_A(0, 0, t2);            // buf0.A0 <- tile 2i+2
    block_bar(); LGKM0();
    mma_quad(acc, a_r, bn1, 0, 1);
    block_bar();

    // ---- P3: Q(m1,n1) ----
    ld_a4(a_r, aBuf[0] + 8192, arow, quad);
    if (!last) STG_B(0, 0, t2);            // buf0.B0
    block_bar(); LGKM0();
    mma_quad(acc, a_r, bn1, 1, 1);
    block_bar();

    // ---- P4: Q(m1,n0) ----
    if (!last) STG_B(0, 1, t2);            // buf0.B1
    block_bar();
    mma_quad(acc, a_r, bn0, 1, 0);
    if (last) { VMC(0); } else { VMC(6); } // buf1 (tile 2i+1) fully landed
    block_bar();

    // ---- P5: tile 2i+1, Q(m0,n0) ----
    ld_a4(a_r, aBuf[1],        arow, quad);
    ld_b2(bn0, bBuf[1],        brow, quad);
    if (!last) STG_A(0, 1, t2);            // buf0.A1
    block_bar(); LGKM0();
    mma_quad(acc, a_r, bn0, 0, 0);
    block_bar();

    // ---- P6: Q(m0,n1) ----
    ld_b2(bn1, bBuf[1] + 8192, brow, quad);
    if (!last) STG_A(1, 0, t3);            // buf1.A0 <- tile 2i+3
    block_bar(); LGKM0();
    mma_quad(acc, a_r, bn1, 0, 1);
    block_bar();

    // ---- P7: Q(m1,n1) ----
    ld_a4(a_r, aBuf[1] + 8192, arow, quad);
    if (!last) STG_B(1, 0, t3);            // buf1.B0
    block_bar(); LGKM0();
    mma_quad(acc, a_r, bn1, 1, 1);
    block_bar();

    // ---- P8: Q(m1,n0) ----
    if (!last) STG_B(1, 1, t3);            // buf1.B1
    block_bar();
    mma_quad(acc, a_r, bn0, 1, 0);
    VMC(6);                                // buf0 (tile 2i+2) fully landed
    block_bar();
  }
#undef STG_A
#undef STG_B
}

// epilogue LDS swizzle: 256x256 bf16 tile, chunk ^= (r&31) ^ (r>>5)
__device__ __forceinline__ int eswz(int r, int c) {
  return r * 256 + ((((c >> 3) ^ (r & 31) ^ (r >> 5)) & 31) * 8) + (c & 7);
}

// ---------------- fused QKV GEMM + bias + RoPE + q/k/v scatter -------------
__global__ __launch_bounds__(512, 2) void gemm_qkv(
    const __bf16* __restrict__ A, const __bf16* __restrict__ Bt,
    const float* __restrict__ bias, const int* __restrict__ pos,
    __bf16* __restrict__ qr, __bf16* __restrict__ kr, __bf16* __restrict__ vt,
    int M, int N, int K) {
  __shared__ __bf16 smem[65536];          // 128 KiB
  const int tid = threadIdx.x;
  const int wave = tid >> 6, lane = tid & 63;
  const int quad = lane >> 4, l15 = lane & 15;
  const int wm = (wave >> 2) * 64, wn = (wave & 3) * 32;

  // bijective XCD swizzle: 768 blocks, 96/XCD, m-fast within chunk
  const int orig = blockIdx.x;
  const int swz = (orig & 7) * 96 + (orig >> 3);
  const int m0 = (swz & 15) * 256;
  const int n0 = (swz >> 4) * 256;

  f32x4 acc[8][4];
#pragma unroll
  for (int i = 0; i < 8; ++i)
#pragma unroll
    for (int j = 0; j < 4; ++j) acc[i][j] = (f32x4){0.f, 0.f, 0.f, 0.f};

  core256(A + (size_t)m0 * K, Bt + (size_t)n0 * K, K, smem, acc);

  // ---- acc + bias -> LDS (swizzled) ----
#pragma unroll
  for (int ni = 0; ni < 4; ++ni) {
    const int scol = (ni >> 1) * 128 + wn + (ni & 1) * 16 + l15;
    const float bv = bias[n0 + scol];
#pragma unroll
    for (int mi = 0; mi < 8; ++mi) {
      const int rbase = (mi >> 2) * 128 + wm + (mi & 3) * 16 + quad * 4;
#pragma unroll
      for (int rr = 0; rr < 4; ++rr)
        smem[eswz(rbase + rr, scol)] = (__bf16)(acc[mi][ni][rr] + bv);
    }
  }
  __syncthreads();

  const int reg = n0 >> 12;               // 0=q 1=k 2=v
  const int h0  = (n0 & 4095) >> 7;       // tile covers heads h0, h0+1
  const int b   = m0 >> 11;
  const int s0  = m0 & 2047;

  if (reg == 2) {
    // V: store transposed (d, s), 16B/lane coalesced over s
    __bf16* dst = vt + (size_t)(b * NHD + h0) * HD * SS;
    const int sg = tid & 31, cb = tid >> 5;     // 32 s-groups x 16 col-bases
    for (int p = 0; p < 16; ++p) {
      const int c = cb + 16 * p;                // 0..255
      bf16x8 v8;
#pragma unroll
      for (int e = 0; e < 8; ++e) v8[e] = smem[eswz(sg * 8 + e, c)];
      *(bf16x8*)(dst + (size_t)(c >> 7) * HD * SS + (size_t)(c & 127) * SS +
                 s0 + sg * 8) = v8;
    }
  } else {
    // Q/K: RoPE in fp32, write (b,h,s,d); Q pre-scaled by 1/sqrt(d)
    __bf16* dst = (reg == 0 ? qr : kr) + (size_t)(b * NHD + h0) * SS * HD;
    const float osc = (reg == 0) ? 0.08838834764831845f : 1.0f;
    const int d2 = tid & 63, rb = (tid >> 6) * 32;
    const float freq = expf(-0.14391156831212787f * (float)d2);  // 1e4^(-d2/64)
    for (int i = 0; i < 32; ++i) {
      const int r = rb + i;
      const float p = (float)pos[b * SS + s0 + r];
      float sn, cs;
      sincosf(p * freq, &sn, &cs);
#pragma unroll
      for (int hs = 0; hs < 2; ++hs) {
        const float x1 = (float)smem[eswz(r, hs * 128 + d2)];
        const float x2 = (float)smem[eswz(r, hs * 128 + d2 + 64)];
        __bf16* dr = dst + (size_t)hs * SS * HD + (size_t)(s0 + r) * HD;
        dr[d2]      = (__bf16)((x1 * cs - x2 * sn) * osc);
        dr[d2 + 64] = (__bf16)((x2 * cs + x1 * sn) * osc);
      }
    }
  }
}

// ---------------- plain bf16 GEMM (output projection): C = A * Bt^T --------
__global__ __launch_bounds__(512, 2) void gemm_bt(
    const __bf16* __restrict__ A, const __bf16* __restrict__ Bt,
    float* __restrict__ Cout, int M, int N, int K) {
  __shared__ __bf16 smem[65536];
  const int tid = threadIdx.x;
  const int wave = tid >> 6, lane = tid & 63;
  const int quad = lane >> 4, l15 = lane & 15;
  const int wm = (wave >> 2) * 64, wn = (wave & 3) * 32;

  const int orig = blockIdx.x;                  // 256 blocks, 32/XCD
  const int swz = (orig & 7) * 32 + (orig >> 3);
  const int m0 = (swz & 15) * 256;
  const int n0 = (swz >> 4) * 256;

  f32x4 acc[8][4];
#pragma unroll
  for (int i = 0; i < 8; ++i)
#pragma unroll
    for (int j = 0; j < 4; ++j) acc[i][j] = (f32x4){0.f, 0.f, 0.f, 0.f};

  core256(A + (size_t)m0 * K, Bt + (size_t)n0 * K, K, smem, acc);

#pragma unroll
  for (int mi = 0; mi < 8; ++mi) {
    const int row = m0 + (mi >> 2) * 128 + wm + (mi & 3) * 16 + quad * 4;
#pragma unroll
    for (int ni = 0; ni < 4; ++ni) {
      const int col = n0 + (ni >> 1) * 128 + wn + (ni & 1) * 16 + l15;
#pragma unroll
      for (int rr = 0; rr < 4; ++rr)
        Cout[(size_t)(row + rr) * N + col] = acc[mi][ni][rr];
    }
  }
}

// ---------------- flash attention, causal, pipelined KVBLK=64 --------------
// Per block: 128 q-rows (4 waves x 32), kv-steps of 64.
// K double-buffered (K[kt+1] in flight across the whole iteration, vmcnt(8));
// V single-buffered (V[kt] hidden under the QK phase, vmcnt(4)).
// P per-wave 32x64, XOR-swizzled chunks (reads/writes <=2-way, free).
// LDS 64 KB -> 2 blocks/CU. Counted vmcnt, never 0 mid-loop.
__global__ __launch_bounds__(256, 2) void flash_attn(
    const __bf16* __restrict__ qr, const __bf16* __restrict__ kr,
    const __bf16* __restrict__ vt, __bf16* __restrict__ ctx) {
  __shared__ __bf16 sK[2][64 * 128];    // 2 x 16 KB
  __shared__ __bf16 sV[128 * 64];       // 16 KB  (rows=d, cols=s)
  __shared__ __bf16 sP[4][32 * 64];     // 16 KB  (per-wave, swizzled)
  const int bh = blockIdx.x;            // 0..63
  const int qt = 15 - blockIdx.y;       // long blocks dispatch first
  const int b = bh >> 5, h = bh & 31;
  const int tid = threadIdx.x;
  const int wave = tid >> 6, lane = tid & 63;
  const int quad = lane >> 4, l15 = lane & 15;
  const int q0 = qt * 128;
  const int NT = 2 * qt + 2;            // kv tiles

  const __bf16* qbase = qr + (size_t)bh * SS * HD;
  const __bf16* kbase = kr + (size_t)bh * SS * HD;
  const __bf16* vbase = vt + (size_t)bh * HD * SS;
  __bf16* pw = &sP[wave][0];

#define STG_K(buf_, kt_) do {                                         \
    const __bf16* kb_ = kbase + (size_t)(kt_) * 64 * HD;              \
    _Pragma("unroll")                                                 \
    for (int i_ = 0; i_ < 4; ++i_) {                                  \
      int off_ = tid * 16 + i_ * 4096;                                \
      int r_ = off_ >> 8, cl_ = (off_ >> 4) & 15;                     \
      int cg_ = (cl_ & 8) | ((cl_ & 7) ^ (r_ & 7));                   \
      gl_lds16(kb_ + (size_t)r_ * HD + cg_ * 8, &sK[buf_][0] + (off_ >> 1)); \
    } } while (0)
#define STG_V(kt_) do {                                               \
    const __bf16* vb_ = vbase + (size_t)(kt_) * 64;                   \
    _Pragma("unroll")                                                 \
    for (int i_ = 0; i_ < 4; ++i_) {                                  \
      int off_ = tid * 16 + i_ * 4096;                                \
      int r_ = off_ >> 7, cl_ = (off_ >> 4) & 7;                      \
      int cg_ = cl_ ^ (r_ & 7);                                       \
      gl_lds16(vb_ + (size_t)r_ * SS + cg_ * 8, &sV[0] + (off_ >> 1)); \
    } } while (0)

  // Q fragments (8 global loads)
  bf16x8 qf[2][4];
  for (int im = 0; im < 2; ++im) {
    int row = q0 + wave * 32 + im * 16 + l15;
    for (int ks = 0; ks < 4; ++ks)
      qf[im][ks] = *(const bf16x8*)(qbase + (size_t)row * HD + ks * 32 + quad * 8);
  }

  f32x4 o[2][8];
  for (int im = 0; im < 2; ++im)
    for (int jd = 0; jd < 8; ++jd)
      o[im][jd] = (f32x4){0.f, 0.f, 0.f, 0.f};
  float l_i[2][4];
  for (int im = 0; im < 2; ++im)
    for (int rg = 0; rg < 4; ++rg) l_i[im][rg] = 0.f;

  STG_K(0, 0);                          // prologue: K[0] -> buf 0

  for (int kt = 0; kt < NT; ++kt) {
    const int k0 = kt * 64;
    const bool more = (kt + 1 < NT);

    block_bar();                        // A: prior PV done reading sV
    STG_V(kt);                          // V[kt] (hidden under QK phase)
    if (more) STG_K((kt + 1) & 1, kt + 1);  // K[kt+1] (full iter of slack)
    if (more) { VMC(8); } else { VMC(4); }  // K[kt] (+Q at kt=0) landed
    block_bar();                        // B: K[kt] visible to all waves

    const __bf16* sKc = &sK[kt & 1][0];

    // S = Q K^T  (Q pre-scaled by 1/sqrt(d))
    f32x4 s[2][4];
    for (int im = 0; im < 2; ++im)
      for (int jn = 0; jn < 4; ++jn)
        s[im][jn] = (f32x4){0.f, 0.f, 0.f, 0.f};
    for (int ks = 0; ks < 4; ++ks) {
      bf16x8 kf[4];
      for (int jn = 0; jn < 4; ++jn) {
        int row = jn * 16 + l15;
        int c = ks * 4 + quad;
        int p = (c & 8) | ((c & 7) ^ (row & 7));
        kf[jn] = *(const bf16x8*)(sKc + row * 128 + p * 8);
      }
      for (int im = 0; im < 2; ++im)
        for (int jn = 0; jn < 4; ++jn)
          s[im][jn] = MFMA16(qf[im][ks], kf[jn], s[im][jn]);
    }

    // softmax w/o running max (C layout: row = quad*4+rg, col = lane&15)
    const bool diag = (kt >= 2 * qt);
    for (int im = 0; im < 2; ++im)
      for (int rg = 0; rg < 4; ++rg) {
        int rowg = q0 + wave * 32 + im * 16 + quad * 4 + rg;
        float rs = 0.f;
        for (int jn = 0; jn < 4; ++jn) {
          float p = (diag && (k0 + jn * 16 + l15) > rowg)
                        ? 0.f : __expf(s[im][jn][rg]);
          s[im][jn][rg] = p;
          rs += p;
        }
        for (int d = 1; d < 16; d <<= 1) rs += __shfl_xor(rs, d);
        l_i[im][rg] += rs;
      }

    // P -> own-wave LDS region (XOR-swizzled 16B chunks: c' = c ^ (row&7))
    for (int im = 0; im < 2; ++im)
      for (int jn = 0; jn < 4; ++jn)
        for (int rg = 0; rg < 4; ++rg) {
          int row = im * 16 + quad * 4 + rg;
          int c = jn * 2 + (l15 >> 3);
          pw[row * 64 + ((c ^ (row & 7)) * 8) + (l15 & 7)] =
              (__bf16)s[im][jn][rg];
        }
    LGKM0();                            // own P writes done
    if (more) { VMC(4); } else { VMC(0); }  // V[kt] landed (K[kt+1] flying)
    block_bar();                        // C: V[kt] visible to all waves

    // O += P V   (pf own-wave; vf swizzled)
    for (int ks = 0; ks < 2; ++ks) {
      bf16x8 pf[2], vf[8];
      for (int im = 0; im < 2; ++im) {
        int row = im * 16 + l15;
        pf[im] = *(const bf16x8*)(pw + row * 64 +
                                  (((ks * 4 + quad) ^ (row & 7)) * 8));
      }
      for (int jd = 0; jd < 8; ++jd) {
        int row = jd * 16 + l15;
        vf[jd] = *(const bf16x8*)(&sV[0] + row * 64 +
                                  (((ks * 4 + quad) ^ (row & 7)) * 8));
      }
      for (int im = 0; im < 2; ++im)
        for (int jd = 0; jd < 8; ++jd)
          o[im][jd] = MFMA16(pf[im], vf[jd], o[im][jd]);
    }
  }
#undef STG_K
#undef STG_V

  // epilogue: O/l -> ctx (B,S,H) bf16
  __bf16* cb = ctx + (size_t)(b * SS) * HID + h * HD;
  for (int im = 0; im < 2; ++im)
    for (int rg = 0; rg < 4; ++rg) {
      float inv = 1.0f / l_i[im][rg];
      int row = q0 + wave * 32 + im * 16 + quad * 4 + rg;
      for (int jd = 0; jd < 8; ++jd)
        cb[(size_t)row * HID + jd * 16 + l15] = (__bf16)(o[im][jd][rg] * inv);
    }
}

// ---------------- launcher ----------------
extern "C" void kernel_launch(void* const* d_in, const int* in_sizes, int n_in,
                              void* d_out, int out_size, void* d_ws, size_t ws_size,
                              hipStream_t stream) {
  const float* hs   = (const float*)d_in[0];
  const int*   pos  = (const int*)d_in[1];
  const float* Wqkv = (const float*)d_in[2];
  const float* bqkv = (const float*)d_in[3];
  const float* Wo   = (const float*)d_in[4];

  // workspace layout (256 MiB total):
  //  [0,32M)     hsb (bf16 hidden) -> reused as ctx after gemm_qkv/flash
  //  [32M,128M)  wqkvT (12288x4096 bf16) — live through gemm_qkv
  //  [128M,160M) woT (4096x4096 bf16)
  //  [160M,192M) qr   [192M,224M) kr   [224M,256M) vt
  char* ws = (char*)d_ws;
  const size_t M32 = 33554432;
  __bf16* hsb   = (__bf16*)(ws);
  __bf16* wqkvT = (__bf16*)(ws + M32);
  __bf16* woT   = (__bf16*)(ws + 4 * M32);
  __bf16* qr    = (__bf16*)(ws + 5 * M32);
  __bf16* kr    = (__bf16*)(ws + 6 * M32);
  __bf16* vt    = (__bf16*)(ws + 7 * M32);
  __bf16* ctx   = hsb;

  cvt_bf16<<<(BSZ * HID) / 1024, 256, 0, stream>>>(hs, hsb, BSZ * HID);
  transp_cvt<<<dim3(N3 / 64, HID / 64), 256, 0, stream>>>(Wqkv, wqkvT, HID, N3);
  transp_cvt<<<dim3(HID / 64, HID / 64), 256, 0, stream>>>(Wo, woT, HID, HID);
  gemm_qkv<<<768, 512, 0, stream>>>(hsb, wqkvT, bqkv, pos, qr, kr, vt,
                                    BSZ, N3, HID);
  flash_attn<<<dim3(BB * NHD, SS / 128), 256, 0, stream>>>(qr, kr, vt, ctx);
  gemm_bt<<<256, 512, 0, stream>>>(ctx, woT, (float*)d_out, BSZ, HID, HID);
}

// Round 3
// 954.497 us; speedup vs baseline: 1.2254x; 1.0010x over previous
//
#include <hip/hip_runtime.h>
#include <stdint.h>

#define HID 4096
#define NHD 32
#define HD  128
#define BB  2
#define SS  2048
#define BSZ (BB*SS)      // 4096 rows (b,s)
#define N3  (3*HID)      // 12288

typedef __bf16 bf16x8 __attribute__((ext_vector_type(8)));
typedef __bf16 bf16x4 __attribute__((ext_vector_type(4)));
typedef float  f32x4  __attribute__((ext_vector_type(4)));

#define MFMA16(A,B,C) __builtin_amdgcn_mfma_f32_16x16x32_bf16((A),(B),(C),0,0,0)

// async global->LDS, 16B per lane; LDS dest must be wave-uniform base + lane*16
__device__ __forceinline__ void gl_lds16(const __bf16* g, __bf16* l) {
  __builtin_amdgcn_global_load_lds(
      (__attribute__((address_space(1))) void*)g,
      (__attribute__((address_space(3))) void*)l, 16, 0, 0);
}

__device__ __forceinline__ void block_bar() {
  __builtin_amdgcn_sched_barrier(0);
  __builtin_amdgcn_s_barrier();
  __builtin_amdgcn_sched_barrier(0);
}
#define LGKM0() do { asm volatile("s_waitcnt lgkmcnt(0)" ::: "memory"); \
                     __builtin_amdgcn_sched_barrier(0); } while (0)
#define VMC(n)  do { asm volatile("s_waitcnt vmcnt(" #n ")" ::: "memory"); \
                     __builtin_amdgcn_sched_barrier(0); } while (0)

// ---------------- elementwise fp32 -> bf16 ----------------
__global__ void cvt_bf16(const float* __restrict__ in, __bf16* __restrict__ out, int n) {
  int i = (blockIdx.x * blockDim.x + threadIdx.x) * 4;
  if (i >= n) return;
  float4 v = *(const float4*)(in + i);
  bf16x4 r;
  r[0] = (__bf16)v.x; r[1] = (__bf16)v.y; r[2] = (__bf16)v.z; r[3] = (__bf16)v.w;
  *(bf16x4*)(out + i) = r;
}

// ------- fp32 (R,C) -> bf16 (C,R) transpose-convert, 64x64 tile, vectorized
__global__ void transp_cvt(const float* __restrict__ in, __bf16* __restrict__ out,
                           int R, int C) {
  __shared__ float t[64 * 65];
  int c0 = blockIdx.x * 64, r0 = blockIdx.y * 64;
  int tx = threadIdx.x & 15, ty = threadIdx.x >> 4;   // 16 x 16
  for (int j = 0; j < 4; ++j) {
    float4 v = *(const float4*)(in + (size_t)(r0 + ty + 16 * j) * C + c0 + tx * 4);
    float* d = t + (ty + 16 * j) * 65 + tx * 4;
    d[0] = v.x; d[1] = v.y; d[2] = v.z; d[3] = v.w;
  }
  __syncthreads();
  for (int j = 0; j < 4; ++j) {
    int cc = ty + 16 * j;                 // transposed output row
    bf16x4 o4;
    for (int e = 0; e < 4; ++e) o4[e] = (__bf16)t[(tx * 4 + e) * 65 + cc];
    *(bf16x4*)(out + (size_t)(c0 + cc) * R + r0 + tx * 4) = o4;
  }
}

// =================== 256x256 8-phase GEMM core (BK=64, 8 waves) ============
// (unchanged)

__device__ __forceinline__ void ld_a4(bf16x8 a[4][2], const __bf16* base, int row, int quad) {
#pragma unroll
  for (int m = 0; m < 4; ++m) {
    const int rr = row + m * 16;
    const int sw = rr & 7;
#pragma unroll
    for (int kk = 0; kk < 2; ++kk)
      a[m][kk] = *(const bf16x8*)(base + rr * 64 + ((kk * 4 + quad) ^ sw) * 8);
  }
}
__device__ __forceinline__ void ld_b2(bf16x8 b[2][2], const __bf16* base, int row, int quad) {
#pragma unroll
  for (int n = 0; n < 2; ++n) {
    const int rr = row + n * 16;
    const int sw = rr & 7;
#pragma unroll
    for (int kk = 0; kk < 2; ++kk)
      b[n][kk] = *(const bf16x8*)(base + rr * 64 + ((kk * 4 + quad) ^ sw) * 8);
  }
}
__device__ __forceinline__ void mma_quad(f32x4 acc[8][4], bf16x8 a[4][2],
                                         bf16x8 b[2][2], int mh, int nh) {
  __builtin_amdgcn_s_setprio(1);
#pragma unroll
  for (int m = 0; m < 4; ++m)
#pragma unroll
    for (int n = 0; n < 2; ++n) {
      f32x4 c = acc[mh * 4 + m][nh * 2 + n];
      c = MFMA16(a[m][0], b[n][0], c);
      c = MFMA16(a[m][1], b[n][1], c);
      acc[mh * 4 + m][nh * 2 + n] = c;
    }
  __builtin_amdgcn_s_setprio(0);
}

__device__ __forceinline__ void core256(const __bf16* __restrict__ Ab,
                                        const __bf16* __restrict__ Bb,
                                        int K, __bf16* smem, f32x4 acc[8][4]) {
  const int tid  = threadIdx.x;
  const int wave = tid >> 6, lane = tid & 63;
  const int quad = lane >> 4, l15 = lane & 15;
  const int arow = ((wave >> 2) * 64) + l15;  // row base within A half-region
  const int brow = ((wave & 3) * 32) + l15;   // row base within B half-region
  const int NKT = K >> 6, NIT = NKT >> 1;

  __bf16* aBuf[2] = { smem,          smem + 16384 };
  __bf16* bBuf[2] = { smem + 32768,  smem + 49152 };

  // per-thread staging offsets (2 x 16B per half-tile)
  const int off0 = tid * 16, off1 = off0 + 8192;
  const int r0 = off0 >> 7, r1 = off1 >> 7;
  const int sO0 = r0 * K + ((((off0 >> 4) & 7) ^ (r0 & 7)) * 8);
  const int sO1 = r1 * K + ((((off1 >> 4) & 7) ^ (r1 & 7)) * 8);
  const int d0 = off0 >> 1, d1 = off1 >> 1;

#define STG_A(buf, half, kt) do { \
    const __bf16* s_ = Ab + (size_t)(half) * 128 * K + (size_t)(kt) * 64; \
    gl_lds16(s_ + sO0, aBuf[buf] + (half) * 8192 + d0); \
    gl_lds16(s_ + sO1, aBuf[buf] + (half) * 8192 + d1); } while (0)
#define STG_B(buf, half, kt) do { \
    const __bf16* s_ = Bb + (size_t)(half) * 128 * K + (size_t)(kt) * 64; \
    gl_lds16(s_ + sO0, bBuf[buf] + (half) * 8192 + d0); \
    gl_lds16(s_ + sO1, bBuf[buf] + (half) * 8192 + d1); } while (0)

  bf16x8 a_r[4][2], bn0[2][2], bn1[2][2];

  // prologue: tile0 [A0,B0,B1,A1]->buf0; tile1 [A0,B0,B1]->buf1
  STG_A(0, 0, 0); STG_B(0, 0, 0); STG_B(0, 1, 0); STG_A(0, 1, 0);
  STG_A(1, 0, 1); STG_B(1, 0, 1); STG_B(1, 1, 1);
  VMC(6);            // tile0 fully landed (tile1's 3 half-tiles may fly)
  block_bar();

  for (int i = 0; i < NIT; ++i) {
    const bool last = (i == NIT - 1);
    const int t1 = 2 * i + 1, t2 = 2 * i + 2, t3 = 2 * i + 3;

    // ---- P1: tile 2i, Q(m0,n0) ----
    ld_a4(a_r, aBuf[0],        arow, quad);
    ld_b2(bn0, bBuf[0],        brow, quad);
    STG_A(1, 1, t1);                       // buf1.A1 <- tile 2i+1 (read at P7)
    block_bar(); LGKM0();
    mma_quad(acc, a_r, bn0, 0, 0);
    block_bar();

    // ---- P2: Q(m0,n1) ----
    ld_b2(bn1, bBuf[0] + 8192, brow, quad);
    if (!last) STG_A(0, 0, t2);            // buf0.A0 <- tile 2i+2
    block_bar(); LGKM0();
    mma_quad(acc, a_r, bn1, 0, 1);
    block_bar();

    // ---- P3: Q(m1,n1) ----
    ld_a4(a_r, aBuf[0] + 8192, arow, quad);
    if (!last) STG_B(0, 0, t2);            // buf0.B0
    block_bar(); LGKM0();
    mma_quad(acc, a_r, bn1, 1, 1);
    block_bar();

    // ---- P4: Q(m1,n0) ----
    if (!last) STG_B(0, 1, t2);            // buf0.B1
    block_bar();
    mma_quad(acc, a_r, bn0, 1, 0);
    if (last) { VMC(0); } else { VMC(6); } // buf1 (tile 2i+1) fully landed
    block_bar();

    // ---- P5: tile 2i+1, Q(m0,n0) ----
    ld_a4(a_r, aBuf[1],        arow, quad);
    ld_b2(bn0, bBuf[1],        brow, quad);
    if (!last) STG_A(0, 1, t2);            // buf0.A1
    block_bar(); LGKM0();
    mma_quad(acc, a_r, bn0, 0, 0);
    block_bar();

    // ---- P6: Q(m0,n1) ----
    ld_b2(bn1, bBuf[1] + 8192, brow, quad);
    if (!last) STG_A(1, 0, t3);            // buf1.A0 <- tile 2i+3
    block_bar(); LGKM0();
    mma_quad(acc, a_r, bn1, 0, 1);
    block_bar();

    // ---- P7: Q(m1,n1) ----
    ld_a4(a_r, aBuf[1] + 8192, arow, quad);
    if (!last) STG_B(1, 0, t3);            // buf1.B0
    block_bar(); LGKM0();
    mma_quad(acc, a_r, bn1, 1, 1);
    block_bar();

    // ---- P8: Q(m1,n0) ----
    if (!last) STG_B(1, 1, t3);            // buf1.B1
    block_bar();
    mma_quad(acc, a_r, bn0, 1, 0);
    VMC(6);                                // buf0 (tile 2i+2) fully landed
    block_bar();
  }
#undef STG_A
#undef STG_B
}

// epilogue LDS swizzle: 256x256 bf16 tile, chunk ^= (r&31) ^ (r>>5)
__device__ __forceinline__ int eswz(int r, int c) {
  return r * 256 + ((((c >> 3) ^ (r & 31) ^ (r >> 5)) & 31) * 8) + (c & 7);
}

// ---------------- fused QKV GEMM + bias + RoPE + q/k/v scatter -------------
__global__ __launch_bounds__(512, 2) void gemm_qkv(
    const __bf16* __restrict__ A, const __bf16* __restrict__ Bt,
    const float* __restrict__ bias, const int* __restrict__ pos,
    __bf16* __restrict__ qr, __bf16* __restrict__ kr, __bf16* __restrict__ vt,
    int M, int N, int K) {
  __shared__ __bf16 smem[65536];          // 128 KiB
  const int tid = threadIdx.x;
  const int wave = tid >> 6, lane = tid & 63;
  const int quad = lane >> 4, l15 = lane & 15;
  const int wm = (wave >> 2) * 64, wn = (wave & 3) * 32;

  // bijective XCD swizzle: 768 blocks, 96/XCD, m-fast within chunk
  const int orig = blockIdx.x;
  const int swz = (orig & 7) * 96 + (orig >> 3);
  const int m0 = (swz & 15) * 256;
  const int n0 = (swz >> 4) * 256;

  f32x4 acc[8][4];
#pragma unroll
  for (int i = 0; i < 8; ++i)
#pragma unroll
    for (int j = 0; j < 4; ++j) acc[i][j] = (f32x4){0.f, 0.f, 0.f, 0.f};

  core256(A + (size_t)m0 * K, Bt + (size_t)n0 * K, K, smem, acc);

  // ---- acc + bias -> LDS (swizzled) ----
#pragma unroll
  for (int ni = 0; ni < 4; ++ni) {
    const int scol = (ni >> 1) * 128 + wn + (ni & 1) * 16 + l15;
    const float bv = bias[n0 + scol];
#pragma unroll
    for (int mi = 0; mi < 8; ++mi) {
      const int rbase = (mi >> 2) * 128 + wm + (mi & 3) * 16 + quad * 4;
#pragma unroll
      for (int rr = 0; rr < 4; ++rr)
        smem[eswz(rbase + rr, scol)] = (__bf16)(acc[mi][ni][rr] + bv);
    }
  }
  __syncthreads();

  const int reg = n0 >> 12;               // 0=q 1=k 2=v
  const int h0  = (n0 & 4095) >> 7;       // tile covers heads h0, h0+1
  const int b   = m0 >> 11;
  const int s0  = m0 & 2047;

  if (reg == 2) {
    // V: store transposed (d, s), 16B/lane coalesced over s
    __bf16* dst = vt + (size_t)(b * NHD + h0) * HD * SS;
    const int sg = tid & 31, cb = tid >> 5;     // 32 s-groups x 16 col-bases
    for (int p = 0; p < 16; ++p) {
      const int c = cb + 16 * p;                // 0..255
      bf16x8 v8;
#pragma unroll
      for (int e = 0; e < 8; ++e) v8[e] = smem[eswz(sg * 8 + e, c)];
      *(bf16x8*)(dst + (size_t)(c >> 7) * HD * SS + (size_t)(c & 127) * SS +
                 s0 + sg * 8) = v8;
    }
  } else {
    // Q/K: RoPE in fp32, write (b,h,s,d); Q pre-scaled by 1/sqrt(d)
    __bf16* dst = (reg == 0 ? qr : kr) + (size_t)(b * NHD + h0) * SS * HD;
    const float osc = (reg == 0) ? 0.08838834764831845f : 1.0f;
    const int d2 = tid & 63, rb = (tid >> 6) * 32;
    const float freq = expf(-0.14391156831212787f * (float)d2);  // 1e4^(-d2/64)
    for (int i = 0; i < 32; ++i) {
      const int r = rb + i;
      const float p = (float)pos[b * SS + s0 + r];
      float sn, cs;
      sincosf(p * freq, &sn, &cs);
#pragma unroll
      for (int hs = 0; hs < 2; ++hs) {
        const float x1 = (float)smem[eswz(r, hs * 128 + d2)];
        const float x2 = (float)smem[eswz(r, hs * 128 + d2 + 64)];
        __bf16* dr = dst + (size_t)hs * SS * HD + (size_t)(s0 + r) * HD;
        dr[d2]      = (__bf16)((x1 * cs - x2 * sn) * osc);
        dr[d2 + 64] = (__bf16)((x2 * cs + x1 * sn) * osc);
      }
    }
  }
}

// ---------------- plain bf16 GEMM (output projection): C = A * Bt^T --------
__global__ __launch_bounds__(512, 2) void gemm_bt(
    const __bf16* __restrict__ A, const __bf16* __restrict__ Bt,
    float* __restrict__ Cout, int M, int N, int K) {
  __shared__ __bf16 smem[65536];
  const int tid = threadIdx.x;
  const int wave = tid >> 6, lane = tid & 63;
  const int quad = lane >> 4, l15 = lane & 15;
  const int wm = (wave >> 2) * 64, wn = (wave & 3) * 32;

  const int orig = blockIdx.x;                  // 256 blocks, 32/XCD
  const int swz = (orig & 7) * 32 + (orig >> 3);
  const int m0 = (swz & 15) * 256;
  const int n0 = (swz >> 4) * 256;

  f32x4 acc[8][4];
#pragma unroll
  for (int i = 0; i < 8; ++i)
#pragma unroll
    for (int j = 0; j < 4; ++j) acc[i][j] = (f32x4){0.f, 0.f, 0.f, 0.f};

  core256(A + (size_t)m0 * K, Bt + (size_t)n0 * K, K, smem, acc);

#pragma unroll
  for (int mi = 0; mi < 8; ++mi) {
    const int row = m0 + (mi >> 2) * 128 + wm + (mi & 3) * 16 + quad * 4;
#pragma unroll
    for (int ni = 0; ni < 4; ++ni) {
      const int col = n0 + (ni >> 1) * 128 + wn + (ni & 1) * 16 + l15;
#pragma unroll
      for (int rr = 0; rr < 4; ++rr)
        Cout[(size_t)(row + rr) * N + col] = acc[mi][ni][rr];
    }
  }
}

// ---------------- flash attention v3: causal, 256-q tiles, 1 barrier/step --
// 8 waves x 32 q-rows. K,V triple-buffered 16KB each (tile kt+2 issued after
// the barrier; vmcnt(4) waits only tile kt -> 2 iterations of slack).
// P round-trip is wave-private (no barrier). Row-sums via MFMA with constant
// all-ones B-frag (no shuffles). Fully-masked waves skip compute.
// Dispatch: 512 blocks (1/CU): first 256 = qt 7..4 (long), second 256 =
// qt 0..3 (LPT balance); same-bh blocks pinned to one XCD.
__global__ __launch_bounds__(512, 2) void flash_attn(
    const __bf16* __restrict__ qr, const __bf16* __restrict__ kr,
    const __bf16* __restrict__ vt, __bf16* __restrict__ ctx) {
  __shared__ __bf16 sK[3][64 * 128];    // 3 x 16 KB
  __shared__ __bf16 sV[3][128 * 64];    // 3 x 16 KB (rows=d, cols=s)
  __shared__ __bf16 sP[8][32 * 64];     // 32 KB (per-wave, swizzled)
  const int blk  = blockIdx.x;
  const int slot = blk & 255, pass = blk >> 8;
  const int xcd  = slot & 7,  jj   = slot >> 3;     // jj 0..31
  const int bh   = xcd + 8 * (jj & 7);              // 0..63, fixed per XCD
  const int qh   = jj >> 3;                         // 0..3
  const int qt   = pass ? qh : 7 - qh;              // long tiles first
  const int b = bh >> 5, h = bh & 31;
  const int tid = threadIdx.x;
  const int wave = tid >> 6, lane = tid & 63;
  const int quad = lane >> 4, l15 = lane & 15;
  const int q0 = qt * 256;
  const int NT = 4 * qt + 4;            // kv tiles of 64
  const int wrow = q0 + wave * 32;      // wave's first q row
  const int wmax = wrow + 31;

  const __bf16* qbase = qr + (size_t)bh * SS * HD;
  const __bf16* kbase = kr + (size_t)bh * SS * HD;
  const __bf16* vbase = vt + (size_t)bh * HD * SS;
  __bf16* pw = &sP[wave][0];

  // staging geometry: 512 threads x 2 x 16B per 16KB tile
  const int offA = tid * 16, offB = offA + 8192;
  const int krA = offA >> 8, kcA = (offA >> 4) & 15;
  const int kgA = (kcA & 8) | ((kcA & 7) ^ (krA & 7));
  const int krB = offB >> 8, kcB = (offB >> 4) & 15;
  const int kgB = (kcB & 8) | ((kcB & 7) ^ (krB & 7));
  const int vrA = offA >> 7, vgA = ((offA >> 4) & 7) ^ (vrA & 7);
  const int vrB = offB >> 7, vgB = ((offB >> 4) & 7) ^ (vrB & 7);

#define STG_KV(buf_, kt_) do {                                            \
    const __bf16* kb_ = kbase + (size_t)(kt_) * 64 * HD;                  \
    gl_lds16(kb_ + krA * HD + kgA * 8, &sK[buf_][0] + (offA >> 1));       \
    gl_lds16(kb_ + krB * HD + kgB * 8, &sK[buf_][0] + (offB >> 1));       \
    const __bf16* vb_ = vbase + (size_t)(kt_) * 64;                       \
    gl_lds16(vb_ + (size_t)vrA * SS + vgA * 8, &sV[buf_][0] + (offA >> 1)); \
    gl_lds16(vb_ + (size_t)vrB * SS + vgB * 8, &sV[buf_][0] + (offB >> 1)); \
  } while (0)

  // Q fragments
  bf16x8 qf[2][4];
#pragma unroll
  for (int im = 0; im < 2; ++im) {
    int row = wrow + im * 16 + l15;
#pragma unroll
    for (int ks = 0; ks < 4; ++ks)
      qf[im][ks] = *(const bf16x8*)(qbase + (size_t)row * HD + ks * 32 + quad * 8);
  }

  bf16x8 onesf;
#pragma unroll
  for (int e = 0; e < 8; ++e) onesf[e] = (__bf16)1.0f;

  f32x4 o[2][8], o_l[2];
#pragma unroll
  for (int im = 0; im < 2; ++im) {
    o_l[im] = (f32x4){0.f, 0.f, 0.f, 0.f};
#pragma unroll
    for (int jd = 0; jd < 8; ++jd)
      o[im][jd] = (f32x4){0.f, 0.f, 0.f, 0.f};
  }

  STG_KV(0, 0); STG_KV(1, 1);           // prologue: tiles 0,1 in flight
  int cur = 0;

  for (int kt = 0; kt < NT; ++kt) {
    const int k0 = kt * 64;
    if (kt + 1 < NT) { VMC(4); } else { VMC(0); }  // tile kt landed
    block_bar();                         // publish K[kt],V[kt]; frees buf kt+2
    if (kt + 2 < NT) {
      int nb = cur + 2; if (nb >= 3) nb -= 3;
      STG_KV(nb, kt + 2);                // 2 iterations of slack
    }

    if (k0 <= wmax) {                    // wave-uniform causal skip
      const __bf16* sKc = &sK[cur][0];
      const __bf16* sVc = &sV[cur][0];

      // S = Q K^T  (Q pre-scaled by 1/sqrt(d))
      f32x4 s[2][4];
#pragma unroll
      for (int im = 0; im < 2; ++im)
#pragma unroll
        for (int jn = 0; jn < 4; ++jn)
          s[im][jn] = (f32x4){0.f, 0.f, 0.f, 0.f};
#pragma unroll
      for (int ks = 0; ks < 4; ++ks) {
        bf16x8 kf[4];
#pragma unroll
        for (int jn = 0; jn < 4; ++jn) {
          int row = jn * 16 + l15;
          int c = ks * 4 + quad;
          int p = (c & 8) | ((c & 7) ^ (row & 7));
          kf[jn] = *(const bf16x8*)(sKc + row * 128 + p * 8);
        }
#pragma unroll
        for (int im = 0; im < 2; ++im)
#pragma unroll
          for (int jn = 0; jn < 4; ++jn)
            s[im][jn] = MFMA16(qf[im][ks], kf[jn], s[im][jn]);
      }

      // exp + causal mask (no running max: scores bounded)
      const bool needm = (k0 + 63 > wrow);
#pragma unroll
      for (int im = 0; im < 2; ++im)
#pragma unroll
        for (int rg = 0; rg < 4; ++rg) {
          int rowg = wrow + im * 16 + quad * 4 + rg;
#pragma unroll
          for (int jn = 0; jn < 4; ++jn) {
            float p = (needm && (k0 + jn * 16 + l15) > rowg)
                          ? 0.f : __expf(s[im][jn][rg]);
            s[im][jn][rg] = p;
          }
        }

      // P -> own-wave LDS (XOR-swizzled chunks); wave-private, no barrier
#pragma unroll
      for (int im = 0; im < 2; ++im)
#pragma unroll
        for (int jn = 0; jn < 4; ++jn)
#pragma unroll
          for (int rg = 0; rg < 4; ++rg) {
            int row = im * 16 + quad * 4 + rg;
            int c = jn * 2 + (l15 >> 3);
            pw[row * 64 + ((c ^ (row & 7)) * 8) + (l15 & 7)] =
                (__bf16)s[im][jn][rg];
          }
      LGKM0();                           // own P writes visible to own reads

      // O += P V ; row-sums via ones-MFMA (same C layout as O)
#pragma unroll
      for (int ks = 0; ks < 2; ++ks) {
        bf16x8 pf[2], vf[8];
#pragma unroll
        for (int im = 0; im < 2; ++im) {
          int row = im * 16 + l15;
          pf[im] = *(const bf16x8*)(pw + row * 64 +
                                    (((ks * 4 + quad) ^ (row & 7)) * 8));
        }
#pragma unroll
        for (int jd = 0; jd < 8; ++jd) {
          int row = jd * 16 + l15;
          vf[jd] = *(const bf16x8*)(sVc + row * 64 +
                                    (((ks * 4 + quad) ^ (row & 7)) * 8));
        }
#pragma unroll
        for (int im = 0; im < 2; ++im) {
#pragma unroll
          for (int jd = 0; jd < 8; ++jd)
            o[im][jd] = MFMA16(pf[im], vf[jd], o[im][jd]);
          o_l[im] = MFMA16(pf[im], onesf, o_l[im]);
        }
      }
    }
    cur = (cur + 1 == 3) ? 0 : cur + 1;
  }
#undef STG_KV

  // epilogue: O / rowsum -> ctx (B,S,H) bf16
  __bf16* cb = ctx + (size_t)(b * SS) * HID + h * HD;
#pragma unroll
  for (int im = 0; im < 2; ++im)
#pragma unroll
    for (int rg = 0; rg < 4; ++rg) {
      float inv = 1.0f / o_l[im][rg];
      int row = wrow + im * 16 + quad * 4 + rg;
#pragma unroll
      for (int jd = 0; jd < 8; ++jd)
        cb[(size_t)row * HID + jd * 16 + l15] = (__bf16)(o[im][jd][rg] * inv);
    }
}

// ---------------- launcher ----------------
extern "C" void kernel_launch(void* const* d_in, const int* in_sizes, int n_in,
                              void* d_out, int out_size, void* d_ws, size_t ws_size,
                              hipStream_t stream) {
  const float* hs   = (const float*)d_in[0];
  const int*   pos  = (const int*)d_in[1];
  const float* Wqkv = (const float*)d_in[2];
  const float* bqkv = (const float*)d_in[3];
  const float* Wo   = (const float*)d_in[4];

  // workspace layout (256 MiB total):
  //  [0,32M)     hsb (bf16 hidden) -> reused as ctx after gemm_qkv/flash
  //  [32M,128M)  wqkvT (12288x4096 bf16) — live through gemm_qkv
  //  [128M,160M) woT (4096x4096 bf16)
  //  [160M,192M) qr   [192M,224M) kr   [224M,256M) vt
  char* ws = (char*)d_ws;
  const size_t M32 = 33554432;
  __bf16* hsb   = (__bf16*)(ws);
  __bf16* wqkvT = (__bf16*)(ws + M32);
  __bf16* woT   = (__bf16*)(ws + 4 * M32);
  __bf16* qr    = (__bf16*)(ws + 5 * M32);
  __bf16* kr    = (__bf16*)(ws + 6 * M32);
  __bf16* vt    = (__bf16*)(ws + 7 * M32);
  __bf16* ctx   = hsb;

  cvt_bf16<<<(BSZ * HID) / 1024, 256, 0, stream>>>(hs, hsb, BSZ * HID);
  transp_cvt<<<dim3(N3 / 64, HID / 64), 256, 0, stream>>>(Wqkv, wqkvT, HID, N3);
  transp_cvt<<<dim3(HID / 64, HID / 64), 256, 0, stream>>>(Wo, woT, HID, HID);
  gemm_qkv<<<768, 512, 0, stream>>>(hsb, wqkvT, bqkv, pos, qr, kr, vt,
                                    BSZ, N3, HID);
  flash_attn<<<512, 512, 0, stream>>>(qr, kr, vt, ctx);
  gemm_bt<<<256, 512, 0, stream>>>(ctx, woT, (float*)d_out, BSZ, HID, HID);
}